// Round 9
// baseline (95.651 us; speedup 1.0000x reference)
//
#include <hip/hip_runtime.h>
#include <stdint.h>

#define B_DIM 4096
#define C_DIM 32
#define D_DIM 128
#define R_DIM 8
#define BM    64           // 4 waves x 16 rows
#define NTHREADS 256

typedef __bf16 bf16x8 __attribute__((ext_vector_type(8)));
typedef float  f32x4  __attribute__((ext_vector_type(4)));

// f32 -> bf16 bits, round-to-nearest-even
__device__ __forceinline__ uint32_t f2bf(float f) {
  uint32_t u = __float_as_uint(f);
  return (u + 0x7FFFu + ((u >> 16) & 1u)) >> 16;
}

#if __has_builtin(__builtin_amdgcn_exp2f)
#define EXP2F(x) __builtin_amdgcn_exp2f(x)
#else
#define EXP2F(x) exp2f(x)
#endif
#if __has_builtin(__builtin_amdgcn_rcpf)
#define RCPF(x) __builtin_amdgcn_rcpf(x)
#else
#define RCPF(x) (1.0f / (x))
#endif

// 16B async global->LDS. LDS dest wave-uniform + lane*16; global addr per-lane.
__device__ __forceinline__ void load_lds16(const void* g, void* l) {
  __builtin_amdgcn_global_load_lds(
      (const __attribute__((address_space(1))) uint32_t*)g,
      (__attribute__((address_space(3))) uint32_t*)l, 16, 0, 0);
}

// DPP row_ror add tree: 16-lane reduction entirely on the VALU pipe.
template <int CTRL>
__device__ __forceinline__ float ror_add(float v) {
  int r = __builtin_amdgcn_update_dpp(0, __builtin_bit_cast(int, v), CTRL, 0xf, 0xf, true);
  return v + __builtin_bit_cast(float, r);
}
__device__ __forceinline__ float red16(float v) {
  v = ror_add<0x128>(v);   // ROW_ROR:8
  v = ror_add<0x124>(v);   // ROW_ROR:4
  v = ror_add<0x122>(v);   // ROW_ROR:2
  v = ror_add<0x121>(v);   // ROW_ROR:1
  return v;
}

// ---- prep 1: W f32 -> bf16, [r][n][kt][lane][8 bf16]: B-frag read for
// (n,kt) is a CONTIGUOUS 1KB block (lane*16 + imm). Conflict-free.
__global__ void prep_w(const float* __restrict__ W, uint32_t* __restrict__ ws) {
  uint32_t t = blockIdx.x * 256u + threadIdx.x;   // 65536 threads, one dword each
  uint32_t c  = t >> 2;
  uint32_t j  = t & 3u;
  uint32_t ln = c & 63u;
  uint32_t kt = (c >> 6) & 3u;
  uint32_t n  = (c >> 8) & 7u;
  uint32_t r  = c >> 11;
  uint32_t o  = n * 16u + (ln & 15u);
  uint32_t k  = kt * 32u + (ln >> 4) * 8u + j * 2u;
  const float2 w2 = *reinterpret_cast<const float2*>(
      W + ((size_t)(r * 128u + o)) * 128u + k);
  ws[t] = f2bf(w2.x) | (f2bf(w2.y) << 16);
}

// ---- prep 2: fold DynamicTanh params, split layout:
// wsA [c][r][col] f32 = a*2log2(e);  wsMC [c][r][col] float2 = {-2c, c+d}
__global__ void prep_acd(const float* __restrict__ A, const float* __restrict__ C,
                         const float* __restrict__ D, float* __restrict__ oA,
                         float2* __restrict__ oMC) {
  uint32_t t = blockIdx.x * 256u + threadIdx.x;   // 32768 threads
  uint32_t col = t & 127u, r = (t >> 7) & 7u, c = t >> 10;
  uint32_t in = (r * 32u + c) * 128u + col;
  float av = A[in], cv = C[in], dv = D[in];
  uint32_t idx = (c * 8u + r) * 128u + col;
  oA[idx]  = av * 2.88539008177793f;
  oMC[idx] = make_float2(-2.f * cv, cv + dv);
}

// One pipeline stage: MFMA V_R (into accCur) interleaved with the epilogue of
// V_{R-1} (in accPrev). Template R keeps ALL acc indexing static (no scratch).
template <int R>
__device__ __forceinline__ void iter_body(
    const uint8_t* __restrict__ wsw, unsigned char* ldsW,
    const float* ldsA, const float2* ldsMC,
    uint32_t lane, uint32_t wid, uint32_t l15,
    const bf16x8 (&af)[4], f32x4 (&x)[8],
    f32x4 (&accCur)[8], f32x4 (&accPrev)[8])
{
  // stage W_{R+1} into the buffer NOT read this iteration (freed by the
  // barrier at the end of iteration R-1); drains under this iteration's work
  if constexpr (R < 7) {
    const uint8_t* g = wsw + (uint32_t)(R + 1) * 32768u;
    unsigned char* lb = ldsW + (uint32_t)(((R + 1) & 1) * 32768);
    #pragma unroll
    for (int j = 0; j < 8; ++j)
      load_lds16(g + wid * 1024u + (uint32_t)j * 4096u + lane * 16u,
                 lb + wid * 1024u + (uint32_t)j * 4096u);
  }

  const unsigned char* bufR = ldsW + (uint32_t)((R & 1) * 32768) + lane * 16u;
  #pragma unroll
  for (int n = 0; n < 8; ++n) accCur[n] = (f32x4){0.f, 0.f, 0.f, 0.f};

  f32x4 s2 = {0.f, 0.f, 0.f, 0.f}, tx = {0.f, 0.f, 0.f, 0.f};
  #pragma unroll
  for (int kt = 0; kt < 4; ++kt) {
    // --- MFMA chunk for V_R: 8 conflict-free ds_read_b128 + 8 MFMA ---
    bf16x8 bq[8];
    #pragma unroll
    for (int n = 0; n < 8; ++n)
      bq[n] = *reinterpret_cast<const bf16x8*>(
          bufR + (uint32_t)((n * 4 + kt) * 1024));
    #pragma unroll
    for (int n = 0; n < 8; ++n)
      accCur[n] = __builtin_amdgcn_mfma_f32_16x16x32_bf16(af[kt], bq[n], accCur[n], 0, 0, 0);

    // --- epilogue chunk of V_{R-1}: 2 column-blocks (VALU/trans pipe) ---
    if constexpr (R >= 1) {
      #pragma unroll
      for (int nn = 0; nn < 2; ++nn) {
        const int n = kt * 2 + nn;
        float  a2 = ldsA [(R - 1) * 128 + n * 16 + l15];
        float2 mc = ldsMC[(R - 1) * 128 + n * 16 + l15];
        f32x4 z = accPrev[n] * a2;
        f32x4 ep;
        #pragma unroll
        for (int q = 0; q < 4; ++q) ep[q] = EXP2F(z[q]);
        ep = ep + 1.0f;
        f32x4 pr;
        #pragma unroll
        for (int q = 0; q < 4; ++q) pr[q] = RCPF(ep[q]);
        f32x4 t = pr * mc.x + mc.y;
        accPrev[n] = t;
        s2 = s2 + t * t;
        tx = tx + t * x[n];
      }
    }
  }
  if constexpr (R >= 1) {
    f32x4 sc;
    #pragma unroll
    for (int q = 0; q < 4; ++q) {
      float s = red16(s2[q]);
      float d = red16(tx[q]);
      sc[q] = -2.f * d * RCPF(fmaxf(s, 1e-24f));
    }
    #pragma unroll
    for (int n = 0; n < 8; ++n)
      x[n] = x[n] + sc * accPrev[n];
  }

  __syncthreads();   // buf[R&1] reads done everywhere; stage W_{R+1} drained
}

__global__ __launch_bounds__(NTHREADS, 2)
void rot_kernel(const float* __restrict__ src, const float* __restrict__ data,
                const uint8_t* __restrict__ wsw, const uint8_t* __restrict__ wsA,
                const uint8_t* __restrict__ wsMC, float* __restrict__ out)
{
  __shared__ __align__(16) unsigned char ldsW[2 * 32768];  // W double-buffer
  __shared__ __align__(16) float  ldsA[8 * 128];           // 4 KB a2
  __shared__ __align__(16) float2 ldsMC[8 * 128];          // 8 KB {-2c, c+d}

  const uint32_t tid  = threadIdx.x;
  const uint32_t lane = tid & 63u;
  const uint32_t wid  = tid >> 6;     // wave 0..3, owns 16 rows
  const uint32_t l15  = lane & 15u;
  const uint32_t lg   = lane >> 4;

  const uint32_t c0   = blockIdx.x & 31u;
  const uint32_t rowb = (blockIdx.x >> 5) * BM + wid * 16u;

  // ---- stage W_0 -> buf0 + acd tables for this c0 ----
  #pragma unroll
  for (int j = 0; j < 8; ++j)
    load_lds16(wsw + wid * 1024u + (uint32_t)j * 4096u + lane * 16u,
               &ldsW[wid * 1024u + (uint32_t)j * 4096u]);
  load_lds16(wsA + (uint32_t)c0 * 4096u + wid * 1024u + lane * 16u,
             (uint8_t*)ldsA + wid * 1024u);
  #pragma unroll
  for (int j = 0; j < 2; ++j)
    load_lds16(wsMC + (uint32_t)c0 * 8192u + wid * 1024u + (uint32_t)j * 4096u + lane * 16u,
               (uint8_t*)ldsMC + wid * 1024u + (uint32_t)j * 4096u);

  // ---- x (data) in registers, MFMA C/D fragment layout ----
  f32x4 x[8];
  #pragma unroll
  for (int q = 0; q < 4; ++q) {
    const float* xr = data + ((size_t)(rowb + lg * 4 + q) * C_DIM + c0) * D_DIM;
    #pragma unroll
    for (int n = 0; n < 8; ++n) x[n][q] = xr[n * 16 + l15];
  }

  // ---- source A-fragments (bf16, converted once) ----
  bf16x8 af[4];
  {
    const float* sr = src + ((size_t)(rowb + l15) * C_DIM + c0) * D_DIM + lg * 8u;
    #pragma unroll
    for (int kt = 0; kt < 4; ++kt) {
      float4 f0 = *reinterpret_cast<const float4*>(sr + kt * 32);
      float4 f1 = *reinterpret_cast<const float4*>(sr + kt * 32 + 4);
      union { uint32_t u[4]; bf16x8 v; } p;
      p.u[0] = f2bf(f0.x) | (f2bf(f0.y) << 16);
      p.u[1] = f2bf(f0.z) | (f2bf(f0.w) << 16);
      p.u[2] = f2bf(f1.x) | (f2bf(f1.y) << 16);
      p.u[3] = f2bf(f1.z) | (f2bf(f1.w) << 16);
      af[kt] = p.v;
    }
  }

  __syncthreads();   // vmcnt(0) drain: W_0 + acd in LDS

  f32x4 accA[8], accB[8];
  iter_body<0>(wsw, ldsW, ldsA, ldsMC, lane, wid, l15, af, x, accA, accB);
  iter_body<1>(wsw, ldsW, ldsA, ldsMC, lane, wid, l15, af, x, accB, accA);
  iter_body<2>(wsw, ldsW, ldsA, ldsMC, lane, wid, l15, af, x, accA, accB);
  iter_body<3>(wsw, ldsW, ldsA, ldsMC, lane, wid, l15, af, x, accB, accA);
  iter_body<4>(wsw, ldsW, ldsA, ldsMC, lane, wid, l15, af, x, accA, accB);
  iter_body<5>(wsw, ldsW, ldsA, ldsMC, lane, wid, l15, af, x, accB, accA);
  iter_body<6>(wsw, ldsW, ldsA, ldsMC, lane, wid, l15, af, x, accA, accB);
  iter_body<7>(wsw, ldsW, ldsA, ldsMC, lane, wid, l15, af, x, accB, accA);

  // ---- final epilogue: V_7 is in accB ----
  {
    f32x4 s2 = {0.f,0.f,0.f,0.f}, tx = {0.f,0.f,0.f,0.f};
    #pragma unroll
    for (int n = 0; n < 8; ++n) {
      float  a2 = ldsA [7 * 128 + n * 16 + l15];
      float2 mc = ldsMC[7 * 128 + n * 16 + l15];
      f32x4 z = accB[n] * a2;
      f32x4 ep;
      #pragma unroll
      for (int q = 0; q < 4; ++q) ep[q] = EXP2F(z[q]);
      ep = ep + 1.0f;
      f32x4 pr;
      #pragma unroll
      for (int q = 0; q < 4; ++q) pr[q] = RCPF(ep[q]);
      f32x4 t = pr * mc.x + mc.y;
      accB[n] = t;
      s2 = s2 + t * t;
      tx = tx + t * x[n];
    }
    f32x4 sc;
    #pragma unroll
    for (int q = 0; q < 4; ++q) {
      float s = red16(s2[q]);
      float d = red16(tx[q]);
      sc[q] = -2.f * d * RCPF(fmaxf(s, 1e-24f));
    }
    #pragma unroll
    for (int n = 0; n < 8; ++n)
      x[n] = x[n] + sc * accB[n];
  }

  // ---- store ----
  #pragma unroll
  for (int q = 0; q < 4; ++q) {
    float* orow = out + ((size_t)(rowb + lg * 4 + q) * C_DIM + c0) * D_DIM;
    #pragma unroll
    for (int n = 0; n < 8; ++n) orow[n * 16 + l15] = x[n][q];
  }
}

extern "C" void kernel_launch(void* const* d_in, const int* in_sizes, int n_in,
                              void* d_out, int out_size, void* d_ws, size_t ws_size,
                              hipStream_t stream) {
  const float* src  = (const float*)d_in[0];
  const float* data = (const float*)d_in[1];
  const float* W    = (const float*)d_in[2];
  const float* Aa   = (const float*)d_in[3];
  const float* Cc   = (const float*)d_in[4];
  const float* Dd   = (const float*)d_in[5];
  float* out = (float*)d_out;

  uint8_t* wsW  = (uint8_t*)d_ws;              // 256 KB bf16 W, frag-ordered
  uint8_t* wsA  = wsW + 262144;                // 128 KB a2 table
  uint8_t* wsMC = wsA + 131072;                // 256 KB {-2c, c+d} table

  prep_w<<<dim3(256), dim3(256), 0, stream>>>(W, (uint32_t*)wsW);
  prep_acd<<<dim3(128), dim3(256), 0, stream>>>(Aa, Cc, Dd, (float*)wsA, (float2*)wsMC);

  dim3 grid((B_DIM / BM) * C_DIM);   // 2048 workgroups of 256
  dim3 block(NTHREADS);
  rot_kernel<<<grid, block, 0, stream>>>(src, data, wsW, wsA, wsMC, out);
}

// Round 10
// 94.562 us; speedup vs baseline: 1.0115x; 1.0115x over previous
//
#include <hip/hip_runtime.h>
#include <stdint.h>

#define B_DIM 4096
#define C_DIM 32
#define D_DIM 128
#define R_DIM 8
#define BM    64           // 4 waves x 16 rows
#define NTHREADS 256

typedef __bf16 bf16x8 __attribute__((ext_vector_type(8)));
typedef float  f32x4  __attribute__((ext_vector_type(4)));

// f32 -> bf16 bits, round-to-nearest-even
__device__ __forceinline__ uint32_t f2bf(float f) {
  uint32_t u = __float_as_uint(f);
  return (u + 0x7FFFu + ((u >> 16) & 1u)) >> 16;
}

#if __has_builtin(__builtin_amdgcn_exp2f)
#define EXP2F(x) __builtin_amdgcn_exp2f(x)
#else
#define EXP2F(x) exp2f(x)
#endif
#if __has_builtin(__builtin_amdgcn_rcpf)
#define RCPF(x) __builtin_amdgcn_rcpf(x)
#else
#define RCPF(x) (1.0f / (x))
#endif

// 16B async global->LDS. LDS dest wave-uniform + lane*16; global addr per-lane.
__device__ __forceinline__ void load_lds16(const void* g, void* l) {
  __builtin_amdgcn_global_load_lds(
      (const __attribute__((address_space(1))) uint32_t*)g,
      (__attribute__((address_space(3))) uint32_t*)l, 16, 0, 0);
}

// DPP row_ror add tree: 16-lane reduction entirely on the VALU pipe.
template <int CTRL>
__device__ __forceinline__ float ror_add(float v) {
  int r = __builtin_amdgcn_update_dpp(0, __builtin_bit_cast(int, v), CTRL, 0xf, 0xf, true);
  return v + __builtin_bit_cast(float, r);
}
__device__ __forceinline__ float red16(float v) {
  v = ror_add<0x128>(v);   // ROW_ROR:8
  v = ror_add<0x124>(v);   // ROW_ROR:4
  v = ror_add<0x122>(v);   // ROW_ROR:2
  v = ror_add<0x121>(v);   // ROW_ROR:1
  return v;
}

// ---- prep 1: W f32 -> bf16, [r][n][kt][lane][8 bf16]: B-frag read for
// (n,kt) is a CONTIGUOUS 1KB block (lane*16 + imm). Conflict-free.
__global__ void prep_w(const float* __restrict__ W, uint32_t* __restrict__ ws) {
  uint32_t t = blockIdx.x * 256u + threadIdx.x;   // 65536 threads, one dword each
  uint32_t c  = t >> 2;
  uint32_t j  = t & 3u;
  uint32_t ln = c & 63u;
  uint32_t kt = (c >> 6) & 3u;
  uint32_t n  = (c >> 8) & 7u;
  uint32_t r  = c >> 11;
  uint32_t o  = n * 16u + (ln & 15u);
  uint32_t k  = kt * 32u + (ln >> 4) * 8u + j * 2u;
  const float2 w2 = *reinterpret_cast<const float2*>(
      W + ((size_t)(r * 128u + o)) * 128u + k);
  ws[t] = f2bf(w2.x) | (f2bf(w2.y) << 16);
}

// ---- prep 2: fold DynamicTanh params, split layout:
// wsA [c][r][col] f32 = a*2log2(e);  wsMC [c][r][col] float2 = {-2c, c+d}
__global__ void prep_acd(const float* __restrict__ A, const float* __restrict__ C,
                         const float* __restrict__ D, float* __restrict__ oA,
                         float2* __restrict__ oMC) {
  uint32_t t = blockIdx.x * 256u + threadIdx.x;   // 32768 threads
  uint32_t col = t & 127u, r = (t >> 7) & 7u, c = t >> 10;
  uint32_t in = (r * 32u + c) * 128u + col;
  float av = A[in], cv = C[in], dv = D[in];
  uint32_t idx = (c * 8u + r) * 128u + col;
  oA[idx]  = av * 2.88539008177793f;
  oMC[idx] = make_float2(-2.f * cv, cv + dv);
}

// One pipeline stage: MFMA V_R (into accCur) interleaved with the epilogue of
// V_{R-1} (in accPrev). Template R keeps ALL acc indexing static (no scratch).
template <int R>
__device__ __forceinline__ void iter_body(
    const uint8_t* __restrict__ wsw, unsigned char* ldsW,
    const float* ldsA, const float2* ldsMC,
    uint32_t lane, uint32_t wid, uint32_t l15,
    const bf16x8 (&af)[4], f32x4 (&x)[8],
    f32x4 (&accCur)[8], f32x4 (&accPrev)[8])
{
  // stage W_{R+1} into the buffer NOT read this iteration (freed by the
  // barrier at the end of iteration R-1); drains under this iteration's work
  if constexpr (R < 7) {
    const uint8_t* g = wsw + (uint32_t)(R + 1) * 32768u;
    unsigned char* lb = ldsW + (uint32_t)(((R + 1) & 1) * 32768);
    #pragma unroll
    for (int j = 0; j < 8; ++j)
      load_lds16(g + wid * 1024u + (uint32_t)j * 4096u + lane * 16u,
                 lb + wid * 1024u + (uint32_t)j * 4096u);
  }

  const unsigned char* bufR = ldsW + (uint32_t)((R & 1) * 32768) + lane * 16u;
  #pragma unroll
  for (int n = 0; n < 8; ++n) accCur[n] = (f32x4){0.f, 0.f, 0.f, 0.f};

  f32x4 s2 = {0.f, 0.f, 0.f, 0.f}, tx = {0.f, 0.f, 0.f, 0.f};
  #pragma unroll
  for (int kt = 0; kt < 4; ++kt) {
    // --- MFMA chunk for V_R: 8 conflict-free ds_read_b128 + 8 MFMA ---
    bf16x8 bq[8];
    #pragma unroll
    for (int n = 0; n < 8; ++n)
      bq[n] = *reinterpret_cast<const bf16x8*>(
          bufR + (uint32_t)((n * 4 + kt) * 1024));
    #pragma unroll
    for (int n = 0; n < 8; ++n)
      accCur[n] = __builtin_amdgcn_mfma_f32_16x16x32_bf16(af[kt], bq[n], accCur[n], 0, 0, 0);

    // --- epilogue chunk of V_{R-1}: 2 column-blocks (VALU/trans pipe) ---
    if constexpr (R >= 1) {
      #pragma unroll
      for (int nn = 0; nn < 2; ++nn) {
        const int n = kt * 2 + nn;
        float  a2 = ldsA [(R - 1) * 128 + n * 16 + l15];
        float2 mc = ldsMC[(R - 1) * 128 + n * 16 + l15];
        f32x4 z = accPrev[n] * a2;
        f32x4 ep;
        #pragma unroll
        for (int q = 0; q < 4; ++q) ep[q] = EXP2F(z[q]);
        ep = ep + 1.0f;
        f32x4 pr;
        #pragma unroll
        for (int q = 0; q < 4; ++q) pr[q] = RCPF(ep[q]);
        f32x4 t = pr * mc.x + mc.y;
        accPrev[n] = t;
        s2 = s2 + t * t;
        tx = tx + t * x[n];
      }
    }
  }
  if constexpr (R >= 1) {
    f32x4 sc;
    #pragma unroll
    for (int q = 0; q < 4; ++q) {
      float s = red16(s2[q]);
      float d = red16(tx[q]);
      sc[q] = -2.f * d * RCPF(fmaxf(s, 1e-24f));
    }
    #pragma unroll
    for (int n = 0; n < 8; ++n)
      x[n] = x[n] + sc * accPrev[n];
  }

  __syncthreads();   // buf[R&1] reads done everywhere; stage W_{R+1} drained
}

__global__ __launch_bounds__(NTHREADS, 2)
void rot_kernel(const float* __restrict__ src, const float* __restrict__ data,
                const uint8_t* __restrict__ wsw, const uint8_t* __restrict__ wsA,
                const uint8_t* __restrict__ wsMC, float* __restrict__ out)
{
  __shared__ __align__(16) unsigned char ldsW[2 * 32768];  // W double-buffer
  __shared__ __align__(16) float  ldsA[8 * 128];           // 4 KB a2
  __shared__ __align__(16) float2 ldsMC[8 * 128];          // 8 KB {-2c, c+d}

  const uint32_t tid  = threadIdx.x;
  const uint32_t lane = tid & 63u;
  const uint32_t wid  = tid >> 6;     // wave 0..3, owns 16 rows
  const uint32_t l15  = lane & 15u;
  const uint32_t lg   = lane >> 4;

  const uint32_t c0   = blockIdx.x & 31u;
  const uint32_t rowb = (blockIdx.x >> 5) * BM + wid * 16u;

  // ---- stage W_0 -> buf0 + acd tables for this c0 ----
  #pragma unroll
  for (int j = 0; j < 8; ++j)
    load_lds16(wsw + wid * 1024u + (uint32_t)j * 4096u + lane * 16u,
               &ldsW[wid * 1024u + (uint32_t)j * 4096u]);
  load_lds16(wsA + (uint32_t)c0 * 4096u + wid * 1024u + lane * 16u,
             (uint8_t*)ldsA + wid * 1024u);
  #pragma unroll
  for (int j = 0; j < 2; ++j)
    load_lds16(wsMC + (uint32_t)c0 * 8192u + wid * 1024u + (uint32_t)j * 4096u + lane * 16u,
               (uint8_t*)ldsMC + wid * 1024u + (uint32_t)j * 4096u);

  // ---- x (data) in registers, MFMA C/D fragment layout ----
  f32x4 x[8];
  #pragma unroll
  for (int q = 0; q < 4; ++q) {
    const float* xr = data + ((size_t)(rowb + lg * 4 + q) * C_DIM + c0) * D_DIM;
    #pragma unroll
    for (int n = 0; n < 8; ++n) x[n][q] = xr[n * 16 + l15];
  }

  // ---- source A-fragments (bf16, converted once) ----
  bf16x8 af[4];
  {
    const float* sr = src + ((size_t)(rowb + l15) * C_DIM + c0) * D_DIM + lg * 8u;
    #pragma unroll
    for (int kt = 0; kt < 4; ++kt) {
      float4 f0 = *reinterpret_cast<const float4*>(sr + kt * 32);
      float4 f1 = *reinterpret_cast<const float4*>(sr + kt * 32 + 4);
      union { uint32_t u[4]; bf16x8 v; } p;
      p.u[0] = f2bf(f0.x) | (f2bf(f0.y) << 16);
      p.u[1] = f2bf(f0.z) | (f2bf(f0.w) << 16);
      p.u[2] = f2bf(f1.x) | (f2bf(f1.y) << 16);
      p.u[3] = f2bf(f1.z) | (f2bf(f1.w) << 16);
      af[kt] = p.v;
    }
  }

  __syncthreads();   // vmcnt(0) drain: W_0 + acd in LDS

  f32x4 accA[8], accB[8];
  iter_body<0>(wsw, ldsW, ldsA, ldsMC, lane, wid, l15, af, x, accA, accB);
  iter_body<1>(wsw, ldsW, ldsA, ldsMC, lane, wid, l15, af, x, accB, accA);
  iter_body<2>(wsw, ldsW, ldsA, ldsMC, lane, wid, l15, af, x, accA, accB);
  iter_body<3>(wsw, ldsW, ldsA, ldsMC, lane, wid, l15, af, x, accB, accA);
  iter_body<4>(wsw, ldsW, ldsA, ldsMC, lane, wid, l15, af, x, accA, accB);
  iter_body<5>(wsw, ldsW, ldsA, ldsMC, lane, wid, l15, af, x, accB, accA);
  iter_body<6>(wsw, ldsW, ldsA, ldsMC, lane, wid, l15, af, x, accA, accB);
  iter_body<7>(wsw, ldsW, ldsA, ldsMC, lane, wid, l15, af, x, accB, accA);

  // ---- final epilogue: V_7 is in accB ----
  {
    f32x4 s2 = {0.f,0.f,0.f,0.f}, tx = {0.f,0.f,0.f,0.f};
    #pragma unroll
    for (int n = 0; n < 8; ++n) {
      float  a2 = ldsA [7 * 128 + n * 16 + l15];
      float2 mc = ldsMC[7 * 128 + n * 16 + l15];
      f32x4 z = accB[n] * a2;
      f32x4 ep;
      #pragma unroll
      for (int q = 0; q < 4; ++q) ep[q] = EXP2F(z[q]);
      ep = ep + 1.0f;
      f32x4 pr;
      #pragma unroll
      for (int q = 0; q < 4; ++q) pr[q] = RCPF(ep[q]);
      f32x4 t = pr * mc.x + mc.y;
      accB[n] = t;
      s2 = s2 + t * t;
      tx = tx + t * x[n];
    }
    f32x4 sc;
    #pragma unroll
    for (int q = 0; q < 4; ++q) {
      float s = red16(s2[q]);
      float d = red16(tx[q]);
      sc[q] = -2.f * d * RCPF(fmaxf(s, 1e-24f));
    }
    #pragma unroll
    for (int n = 0; n < 8; ++n)
      x[n] = x[n] + sc * accB[n];
  }

  // ---- store ----
  #pragma unroll
  for (int q = 0; q < 4; ++q) {
    float* orow = out + ((size_t)(rowb + lg * 4 + q) * C_DIM + c0) * D_DIM;
    #pragma unroll
    for (int n = 0; n < 8; ++n) orow[n * 16 + l15] = x[n][q];
  }
}

extern "C" void kernel_launch(void* const* d_in, const int* in_sizes, int n_in,
                              void* d_out, int out_size, void* d_ws, size_t ws_size,
                              hipStream_t stream) {
  const float* src  = (const float*)d_in[0];
  const float* data = (const float*)d_in[1];
  const float* W    = (const float*)d_in[2];
  const float* Aa   = (const float*)d_in[3];
  const float* Cc   = (const float*)d_in[4];
  const float* Dd   = (const float*)d_in[5];
  float* out = (float*)d_out;

  uint8_t* wsW  = (uint8_t*)d_ws;              // 256 KB bf16 W, frag-ordered
  uint8_t* wsA  = wsW + 262144;                // 128 KB a2 table
  uint8_t* wsMC = wsA + 131072;                // 256 KB {-2c, c+d} table

  prep_w<<<dim3(256), dim3(256), 0, stream>>>(W, (uint32_t*)wsW);
  prep_acd<<<dim3(128), dim3(256), 0, stream>>>(Aa, Cc, Dd, (float*)wsA, (float2*)wsMC);

  dim3 grid((B_DIM / BM) * C_DIM);   // 2048 workgroups of 256
  dim3 block(NTHREADS);
  rot_kernel<<<grid, block, 0, stream>>>(src, data, wsW, wsA, wsMC, out);
}

// Round 11
// 82.847 us; speedup vs baseline: 1.1545x; 1.1414x over previous
//
#include <hip/hip_runtime.h>
#include <stdint.h>

#define B_DIM 4096
#define C_DIM 32
#define D_DIM 128
#define R_DIM 8
#define BM    64           // 4 waves x 16 rows
#define NTHREADS 256

typedef __bf16 bf16x8 __attribute__((ext_vector_type(8)));
typedef float  f32x4  __attribute__((ext_vector_type(4)));

// f32 -> bf16 bits, round-to-nearest-even
__device__ __forceinline__ uint32_t f2bf(float f) {
  uint32_t u = __float_as_uint(f);
  return (u + 0x7FFFu + ((u >> 16) & 1u)) >> 16;
}

#if __has_builtin(__builtin_amdgcn_exp2f)
#define EXP2F(x) __builtin_amdgcn_exp2f(x)
#else
#define EXP2F(x) exp2f(x)
#endif
#if __has_builtin(__builtin_amdgcn_rcpf)
#define RCPF(x) __builtin_amdgcn_rcpf(x)
#else
#define RCPF(x) (1.0f / (x))
#endif

// 16B async global->LDS. LDS dest wave-uniform + lane*16; global addr per-lane.
__device__ __forceinline__ void load_lds16(const void* g, void* l) {
  __builtin_amdgcn_global_load_lds(
      (const __attribute__((address_space(1))) uint32_t*)g,
      (__attribute__((address_space(3))) uint32_t*)l, 16, 0, 0);
}

// DPP row_ror add tree: 16-lane reduction entirely on the VALU pipe.
template <int CTRL>
__device__ __forceinline__ float ror_add(float v) {
  int r = __builtin_amdgcn_update_dpp(0, __builtin_bit_cast(int, v), CTRL, 0xf, 0xf, true);
  return v + __builtin_bit_cast(float, r);
}
__device__ __forceinline__ float red16(float v) {
  v = ror_add<0x128>(v);   // ROW_ROR:8
  v = ror_add<0x124>(v);   // ROW_ROR:4
  v = ror_add<0x122>(v);   // ROW_ROR:2
  v = ror_add<0x121>(v);   // ROW_ROR:1
  return v;
}

// ---- prep 1: W f32 -> bf16, [r][n][kt][lane][8 bf16]: B-frag read for
// (n,kt) is a CONTIGUOUS 1KB block (lane*16 + imm). Conflict-free.
__global__ void prep_w(const float* __restrict__ W, uint32_t* __restrict__ ws) {
  uint32_t t = blockIdx.x * 256u + threadIdx.x;   // 65536 threads, one dword each
  uint32_t c  = t >> 2;
  uint32_t j  = t & 3u;
  uint32_t ln = c & 63u;
  uint32_t kt = (c >> 6) & 3u;
  uint32_t n  = (c >> 8) & 7u;
  uint32_t r  = c >> 11;
  uint32_t o  = n * 16u + (ln & 15u);
  uint32_t k  = kt * 32u + (ln >> 4) * 8u + j * 2u;
  const float2 w2 = *reinterpret_cast<const float2*>(
      W + ((size_t)(r * 128u + o)) * 128u + k);
  ws[t] = f2bf(w2.x) | (f2bf(w2.y) << 16);
}

// ---- prep 2: fold DynamicTanh params.
// wsA  [c][r][col] f32 = a*2log2(e)
// wsMC [c][r][col] u32 = bf16(cdv)<<16 | bf16(-2c)   (bf16 halves LDS to 4KB)
__global__ void prep_acd(const float* __restrict__ A, const float* __restrict__ C,
                         const float* __restrict__ D, float* __restrict__ oA,
                         uint32_t* __restrict__ oMC) {
  uint32_t t = blockIdx.x * 256u + threadIdx.x;   // 32768 threads
  uint32_t col = t & 127u, r = (t >> 7) & 7u, c = t >> 10;
  uint32_t in = (r * 32u + c) * 128u + col;
  float av = A[in], cv = C[in], dv = D[in];
  uint32_t idx = (c * 8u + r) * 128u + col;
  oA[idx]  = av * 2.88539008177793f;
  oMC[idx] = (f2bf(cv + dv) << 16) | f2bf(-2.f * cv);
}

__global__ __launch_bounds__(NTHREADS, 4)
void rot_kernel(const float* __restrict__ src, const float* __restrict__ data,
                const uint8_t* __restrict__ wsw, const uint8_t* __restrict__ wsA,
                const uint8_t* __restrict__ wsMC, float* __restrict__ out)
{
  __shared__ __align__(16) unsigned char ldsW[32768];   // single-buffered W_r
  __shared__ __align__(16) float    ldsA[8 * 128];      // 4 KB a2 (f32)
  __shared__ __align__(16) uint32_t ldsMC[8 * 128];     // 4 KB packed bf16 {cdv|m2c}

  const uint32_t tid  = threadIdx.x;
  const uint32_t lane = tid & 63u;
  const uint32_t wid  = tid >> 6;     // wave 0..3, owns 16 rows
  const uint32_t l15  = lane & 15u;
  const uint32_t lg   = lane >> 4;

  const uint32_t c0   = blockIdx.x & 31u;
  const uint32_t rowb = (blockIdx.x >> 5) * BM + wid * 16u;

  // ---- stage W_0 (32KB) + acd tables (8KB) for this c0 ----
  #pragma unroll
  for (int j = 0; j < 8; ++j)
    load_lds16(wsw + wid * 1024u + (uint32_t)j * 4096u + lane * 16u,
               &ldsW[wid * 1024u + (uint32_t)j * 4096u]);
  load_lds16(wsA + (uint32_t)c0 * 4096u + wid * 1024u + lane * 16u,
             (uint8_t*)ldsA + wid * 1024u);
  load_lds16(wsMC + (uint32_t)c0 * 4096u + wid * 1024u + lane * 16u,
             (uint8_t*)ldsMC + wid * 1024u);

  // ---- x (data) in registers, MFMA C/D fragment layout ----
  f32x4 x[8];
  #pragma unroll
  for (int q = 0; q < 4; ++q) {
    const float* xr = data + ((size_t)(rowb + lg * 4 + q) * C_DIM + c0) * D_DIM;
    #pragma unroll
    for (int n = 0; n < 8; ++n) x[n][q] = xr[n * 16 + l15];
  }

  // ---- source A-fragments (bf16, converted once) ----
  bf16x8 af[4];
  {
    const float* sr = src + ((size_t)(rowb + l15) * C_DIM + c0) * D_DIM + lg * 8u;
    #pragma unroll
    for (int kt = 0; kt < 4; ++kt) {
      float4 f0 = *reinterpret_cast<const float4*>(sr + kt * 32);
      float4 f1 = *reinterpret_cast<const float4*>(sr + kt * 32 + 4);
      union { uint32_t u[4]; bf16x8 v; } p;
      p.u[0] = f2bf(f0.x) | (f2bf(f0.y) << 16);
      p.u[1] = f2bf(f0.z) | (f2bf(f0.w) << 16);
      p.u[2] = f2bf(f1.x) | (f2bf(f1.y) << 16);
      p.u[3] = f2bf(f1.z) | (f2bf(f1.w) << 16);
      af[kt] = p.v;
    }
  }

  __syncthreads();   // vmcnt(0) drain: W_0 + acd in LDS

  for (int r = 0; r < R_DIM; ++r) {
    // ---- MFMA phase: V = S @ W_r^T (conflict-free contiguous bq reads) ----
    const uint32_t rb = lane * 16u;
    f32x4 acc[8];
    #pragma unroll
    for (int n = 0; n < 8; ++n) acc[n] = (f32x4){0.f, 0.f, 0.f, 0.f};
    #pragma unroll
    for (int kt = 0; kt < 4; ++kt) {
      #pragma unroll
      for (int nh = 0; nh < 8; nh += 4) {
        bf16x8 bq[4];
        #pragma unroll
        for (int i = 0; i < 4; ++i)
          bq[i] = *reinterpret_cast<const bf16x8*>(
              &ldsW[rb + (uint32_t)(((nh + i) * 4 + kt) * 1024)]);
        #pragma unroll
        for (int i = 0; i < 4; ++i)
          acc[nh + i] = __builtin_amdgcn_mfma_f32_16x16x32_bf16(af[kt], bq[i], acc[nh + i], 0, 0, 0);
      }
    }

    __syncthreads();   // all waves done READING W_r -> safe to overwrite

    // ---- async-split stage of W_{r+1}: issue now, drains under epilogue ----
    if (r < 7) {
      const uint8_t* g = wsw + (uint32_t)(r + 1) * 32768u;
      #pragma unroll
      for (int j = 0; j < 8; ++j)
        load_lds16(g + wid * 1024u + (uint32_t)j * 4096u + lane * 16u,
                   &ldsW[wid * 1024u + (uint32_t)j * 4096u]);
    }

    // ---- epilogue: t = tanh(a*v)*c + d;  x -= 2*t*(t.x)/max(||t||,eps)^2 ----
    f32x4 s2 = {0.f,0.f,0.f,0.f}, tx = {0.f,0.f,0.f,0.f};
    #pragma unroll
    for (int n = 0; n < 8; ++n) {
      float    a2  = ldsA [r * 128 + n * 16 + l15];   // broadcast, conflict-free
      uint32_t mcu = ldsMC[r * 128 + n * 16 + l15];
      float m2c = __builtin_bit_cast(float, mcu << 16);          // bf16 -> f32
      float cdv = __builtin_bit_cast(float, mcu & 0xffff0000u);  // bf16 -> f32
      f32x4 z = acc[n] * a2;
      f32x4 ep;
      #pragma unroll
      for (int q = 0; q < 4; ++q) ep[q] = EXP2F(z[q]);
      ep = ep + 1.0f;
      f32x4 pr;
      #pragma unroll
      for (int q = 0; q < 4; ++q) pr[q] = RCPF(ep[q]);
      f32x4 t = pr * m2c + cdv;
      acc[n] = t;
      s2 = s2 + t * t;
      tx = tx + t * x[n];
    }
    f32x4 sc;
    #pragma unroll
    for (int q = 0; q < 4; ++q) {
      float s = red16(s2[q]);
      float d = red16(tx[q]);
      sc[q] = -2.f * d * RCPF(fmaxf(s, 1e-24f));
    }
    #pragma unroll
    for (int n = 0; n < 8; ++n)
      x[n] = x[n] + sc * acc[n];

    __syncthreads();   // vmcnt(0): W_{r+1} fully landed before next MFMA phase
  }

  // ---- store ----
  #pragma unroll
  for (int q = 0; q < 4; ++q) {
    float* orow = out + ((size_t)(rowb + lg * 4 + q) * C_DIM + c0) * D_DIM;
    #pragma unroll
    for (int n = 0; n < 8; ++n) orow[n * 16 + l15] = x[n][q];
  }
}

extern "C" void kernel_launch(void* const* d_in, const int* in_sizes, int n_in,
                              void* d_out, int out_size, void* d_ws, size_t ws_size,
                              hipStream_t stream) {
  const float* src  = (const float*)d_in[0];
  const float* data = (const float*)d_in[1];
  const float* W    = (const float*)d_in[2];
  const float* Aa   = (const float*)d_in[3];
  const float* Cc   = (const float*)d_in[4];
  const float* Dd   = (const float*)d_in[5];
  float* out = (float*)d_out;

  uint8_t* wsW  = (uint8_t*)d_ws;              // 256 KB bf16 W, frag-ordered
  uint8_t* wsA  = wsW + 262144;                // 128 KB a2 table (f32)
  uint8_t* wsMC = wsA + 131072;                // 128 KB packed bf16 {cdv|m2c}

  prep_w<<<dim3(256), dim3(256), 0, stream>>>(W, (uint32_t*)wsW);
  prep_acd<<<dim3(128), dim3(256), 0, stream>>>(Aa, Cc, Dd, (float*)wsA, (uint32_t*)wsMC);

  dim3 grid((B_DIM / BM) * C_DIM);   // 2048 workgroups of 256
  dim3 block(NTHREADS);
  rot_kernel<<<grid, block, 0, stream>>>(src, data, wsW, wsA, wsMC, out);
}